// Round 10
// baseline (184.771 us; speedup 1.0000x reference)
//
#include <hip/hip_runtime.h>
#include <cstdint>
#include <cstddef>

// DeformConv2d B=8 C=256 H=W=64 Cout=256 K=3 s=1 p=1 d=1
// Round 10: NHWC-bf16 + 32x32x16 MFMA + double-buffered 16-ch chunks.
//  Prepass 1: wperm16 — weight fp32 -> bf16, layout [co][ch16][kk][c_l16]
//  Prepass 2: xpose   — x NCHW fp32 -> NHWC bf16 (xT[b][y][x][c], 16 MB)
//  Main: 512 blocks x 1024 thr (16 waves = 8 cog x 2 pxg). Wave tile
//  32co x 32px via one mfma_f32_32x32x16_bf16 acc (16 regs). 16-ch chunks
//  (K=144 = 9 steps of 16, step = tap kk), cols double-buffered: stage
//  chunk i+1 overlaps MFMA of chunk i (one barrier per chunk).
//  cols row stride 304B (19 x 16B, odd) -> even LDS bank spread.
// Fallback (ws too small): round-6 proven kernel.

#define B_   8
#define C_   256
#define H_   64
#define W_   64
#define CO_  256
#define KK_  9
#define PADK16 152           // 16-ch chunk row: 144 k + pad -> 304B, 19 blocks

typedef short  short8   __attribute__((ext_vector_type(8)));
typedef float  f32x4    __attribute__((ext_vector_type(4)));
typedef float  f32x16   __attribute__((ext_vector_type(16)));
typedef float  f32x2    __attribute__((ext_vector_type(2)));

__device__ inline short f2bf(float f) {   // round-to-nearest-even fp32->bf16
    uint32_t u = __builtin_bit_cast(uint32_t, f);
    u += 0x7FFFu + ((u >> 16) & 1u);
    return (short)(u >> 16);
}
__device__ inline float bf2f(short s) {
    return __builtin_bit_cast(float, (uint32_t)(uint16_t)s << 16);
}

// ---- prepass 1: weight fp32 -> bf16, [co][ch16][kk][c_l16] ----
// octet i = co*288 + ch16*18 + kk*2 + oct8   (288 = 16*9*2)
__global__ __launch_bounds__(256) void wperm16(const float* __restrict__ w,
                                               short* __restrict__ wp) {
    const int i = blockIdx.x * 256 + threadIdx.x;   // 73728 octet tasks
    const int oct8 = i & 1;
    const int kk   = (i >> 1) % 9;
    const int ch16 = ((i >> 1) / 9) & 15;
    const int co   = i / 288;
    short8 v;
#pragma unroll
    for (int j = 0; j < 8; ++j) {
        const int c = ch16 * 16 + oct8 * 8 + j;
        v[j] = f2bf(w[((size_t)(co * C_) + c) * KK_ + kk]);
    }
    *reinterpret_cast<short8*>(wp + (size_t)i * 8) = v;
}

// ---- prepass 2: x NCHW fp32 -> NHWC bf16 ----
__global__ __launch_bounds__(256) void xpose(const float* __restrict__ x,
                                             short* __restrict__ xT) {
    __shared__ short tile[64 * 258];     // [xw][c], +2 pad vs bank conflicts
    const int bid = blockIdx.x;          // 512 = 64*8
    const int y = bid & 63;
    const int b = bid >> 6;
    const int t = threadIdx.x;
    const int c4 = t >> 6;               // 0..3 (wave-uniform)
    const int xw = t & 63;
    const float* src = x + (size_t)b * (C_ * H_ * W_) + (size_t)y * W_ + xw;
#pragma unroll 8
    for (int j = 0; j < 64; ++j) {
        const int c = j * 4 + c4;
        tile[xw * 258 + c] = f2bf(src[(size_t)c * (H_ * W_)]);
    }
    __syncthreads();
    short* dst = xT + ((size_t)(b * (H_ * W_)) + y * W_) * C_;
#pragma unroll
    for (int r = 0; r < 8; ++r) {
        const int idx = r * 256 + t;     // 0..2047 short8 groups
        const int xw2 = idx >> 5;
        const int c2  = (idx & 31) * 8;
        *reinterpret_cast<short8*>(dst + xw2 * C_ + c2) =
            *reinterpret_cast<const short8*>(&tile[xw2 * 258 + c2]);
    }
}

// ---- main ----
__global__ __launch_bounds__(1024, 8) void dcn_mfma4(
    const short* __restrict__ xT,      // [b][y][x][c] bf16, 2MB/batch
    const float* __restrict__ offset,
    const short* __restrict__ wpm,     // [co][ch16][kk][c_l16] bf16
    const float* __restrict__ bias,
    float* __restrict__ out)
{
    __shared__ uint32_t t_pA[KK_ * 64];      // idx00 | idx01<<16
    __shared__ uint32_t t_pB[KK_ * 64];      // idx10 | idx11<<16
    __shared__ f32x4    t_wv[KK_ * 64];      // 4 corner weights (0 if invalid)
    __shared__ short    cols[2][64 * PADK16]; // dbuf: [px][k'], k'=kk*16+c_l

    const int bid = blockIdx.x;          // 512
    const int b   = bid & 7;             // XCD affinity per batch
    const int ho  = bid >> 3;

    const int t    = threadIdx.x;
    const int lane = t & 63;
    const int wave = t >> 6;             // 0..15

    // ---- bilinear tables: one entry per (kk, wo) ----
    if (t < KK_ * 64) {
        const int e  = t;
        const int kk = e >> 6;
        const int wo = e & 63;
        const int ky = kk / 3, kx = kk % 3;
        const float offy = offset[(((b * 18) + kk * 2 + 0) * 64 + ho) * 64 + wo];
        const float offx = offset[(((b * 18) + kk * 2 + 1) * 64 + ho) * 64 + wo];
        const float py  = (float)(ho - 1 + ky) + offy;
        const float pxx = (float)(wo - 1 + kx) + offx;
        const float y0f = floorf(py), x0f = floorf(pxx);
        const float wy = py - y0f, wx = pxx - x0f;
        const int y0 = (int)y0f, x0 = (int)x0f;
        const int y1 = y0 + 1,   x1 = x0 + 1;
        const float vy0 = (y0 >= 0 && y0 < H_) ? 1.f : 0.f;
        const float vy1 = (y1 >= 0 && y1 < H_) ? 1.f : 0.f;
        const float vx0 = (x0 >= 0 && x0 < W_) ? 1.f : 0.f;
        const float vx1 = (x1 >= 0 && x1 < W_) ? 1.f : 0.f;
        f32x4 wv;
        wv[0] = (1.f - wy) * (1.f - wx) * vy0 * vx0;
        wv[1] = (1.f - wy) * wx         * vy0 * vx1;
        wv[2] = wy         * (1.f - wx) * vy1 * vx0;
        wv[3] = wy         * wx         * vy1 * vx1;
        const int y0c = min(max(y0, 0), H_ - 1);
        const int y1c = min(max(y1, 0), H_ - 1);
        const int x0c = min(max(x0, 0), W_ - 1);
        const int x1c = min(max(x1, 0), W_ - 1);
        t_pA[e] = (uint32_t)(y0c * W_ + x0c) | ((uint32_t)(y0c * W_ + x1c) << 16);
        t_pB[e] = (uint32_t)(y1c * W_ + x0c) | ((uint32_t)(y1c * W_ + x1c) << 16);
        t_wv[e] = wv;
    }
    __syncthreads();

    f32x16 acc = (f32x16)0.f;

    const int cog = wave >> 1;           // co-32 group (0..7)
    const int pxg = wave & 1;            // px-32 group
    const int co0 = __builtin_amdgcn_readfirstlane(cog * 32);
    const int px0 = __builtin_amdgcn_readfirstlane(pxg * 32);
    const int m_l = lane & 31;           // row/col within 32x32 fragment
    const int g_l = lane >> 5;           // k half-group (8 k each)

    // weight row base: [co][ch16][kk][c_l16], af = wrow + ch*144 + s*16
    const short* wrow = wpm + (size_t)(co0 + m_l) * (C_ * KK_) + g_l * 8;

    // staging ids: t = kk*128 + px*2 + oct  (kk 0..7), + t<128 -> kk=8
    const int soct = t & 1;              // channel octet within 16-ch chunk
    const int spx  = (t >> 1) & 63;      // px
    const int kk0  = t >> 7;             // 0..7
    const char* xq = (const char*)xT + ((size_t)b << 21) + soct * 16;

#define DO_TASK(KK, XC, BUF) { \
    const int e = (KK) * 64 + spx; \
    const uint32_t pA = t_pA[e]; \
    const uint32_t pB = t_pB[e]; \
    const f32x4 wv = t_wv[e]; \
    short8 s00, s01, s10, s11; \
    __builtin_memcpy(&s00, (XC) + (size_t)(pA & 0xFFFFu) * 512, 16); \
    __builtin_memcpy(&s01, (XC) + (size_t)(pA >> 16)     * 512, 16); \
    __builtin_memcpy(&s10, (XC) + (size_t)(pB & 0xFFFFu) * 512, 16); \
    __builtin_memcpy(&s11, (XC) + (size_t)(pB >> 16)     * 512, 16); \
    short8 vs; \
    _Pragma("unroll") \
    for (int j = 0; j < 8; ++j) { \
        const float v = wv[0] * bf2f(s00[j]) + wv[1] * bf2f(s01[j]) \
                      + wv[2] * bf2f(s10[j]) + wv[3] * bf2f(s11[j]); \
        vs[j] = f2bf(v); \
    } \
    *reinterpret_cast<short8*>(&(BUF)[spx * PADK16 + (KK) * 16 + soct * 8]) = vs; }

#define STAGE(CH, BUF) { \
    const char* xc = xq + (CH) * 32; \
    DO_TASK(kk0, xc, BUF) \
    if (t < 128) { DO_TASK(8, xc, BUF) } }

    STAGE(0, cols[0])
    __syncthreads();

    for (int ch = 0; ch < 16; ++ch) {
        if (ch < 15) { STAGE(ch + 1, cols[(ch + 1) & 1]) }
        const short* rbuf = &cols[ch & 1][0];
        const short* wch  = wrow + ch * 144;
#pragma unroll
        for (int s = 0; s < 9; ++s) {
            short8 af, bf;
            __builtin_memcpy(&af, wch + s * 16, 16);
            __builtin_memcpy(&bf, &rbuf[(px0 + m_l) * PADK16 + s * 16 + g_l * 8], 16);
            acc = __builtin_amdgcn_mfma_f32_32x32x16_bf16(af, bf, acc, 0, 0, 0);
        }
        __syncthreads();
    }

    // ---- epilogue: D col=lane&31 (px), row=(r&3)+8*(r>>2)+4*(lane>>5) (co) ----
    const int px = px0 + m_l;
#pragma unroll
    for (int r = 0; r < 16; ++r) {
        const int co = co0 + (r & 3) + 8 * (r >> 2) + 4 * g_l;
        out[((size_t)(b * CO_ + co) * H_ + ho) * W_ + px] = acc[r] + bias[co];
    }
}

// ================= fallback (round-6 proven path, ws < 18 MB) =================
#define PADK 296
__global__ __launch_bounds__(256) void w2bf_fb(const float* __restrict__ w,
                                               short* __restrict__ wb, int n8) {
    const int i = blockIdx.x * 256 + threadIdx.x;
    if (i >= n8) return;
    const f32x4 a = *reinterpret_cast<const f32x4*>(w + (size_t)i * 8);
    const f32x4 bq = *reinterpret_cast<const f32x4*>(w + (size_t)i * 8 + 4);
    short8 v;
#pragma unroll
    for (int j = 0; j < 4; ++j) { v[j] = f2bf(a[j]); v[j + 4] = f2bf(bq[j]); }
    *reinterpret_cast<short8*>(wb + (size_t)i * 8) = v;
}

__global__ __launch_bounds__(512, 2) void dcn_mfma_fb(
    const float* __restrict__ x,
    const float* __restrict__ offset,
    const short* __restrict__ wbf,
    const float* __restrict__ bias,
    float* __restrict__ out)
{
    __shared__ uint32_t t_oab[KK_ * 64];
    __shared__ f32x4    t_wv[KK_ * 64];
    __shared__ short    colsf[64 * PADK];

    const int bid = blockIdx.x;
    const int ho  = bid & 63;
    const int b   = bid >> 6;
    const int t    = threadIdx.x;
    const int lane = t & 63;
    const int wave = t >> 6;

    for (int e = t; e < KK_ * 64; e += 512) {
        const int kk = e >> 6;
        const int wo = e & 63;
        const int ky = kk / 3, kx = kk % 3;
        const float offy = offset[(((b * 18) + kk * 2 + 0) * 64 + ho) * 64 + wo];
        const float offx = offset[(((b * 18) + kk * 2 + 1) * 64 + ho) * 64 + wo];
        const float py  = (float)(ho - 1 + ky) + offy;
        const float pxx = (float)(wo - 1 + kx) + offx;
        const float y0f = floorf(py), x0f = floorf(pxx);
        const float wy = py - y0f, wx = pxx - x0f;
        const int y0 = (int)y0f, x0 = (int)x0f;
        const int y1 = y0 + 1,   x1 = x0 + 1;
        const float vy0 = (y0 >= 0 && y0 < H_) ? 1.f : 0.f;
        const float vy1 = (y1 >= 0 && y1 < H_) ? 1.f : 0.f;
        const float vx0 = (x0 >= 0 && x0 < W_) ? 1.f : 0.f;
        const float vx1 = (x1 >= 0 && x1 < W_) ? 1.f : 0.f;
        const float wv0 = (1.f - wy) * (1.f - wx) * vy0 * vx0;
        const float wv1 = (1.f - wy) * wx         * vy0 * vx1;
        const float wv2 = wy         * (1.f - wx) * vy1 * vx0;
        const float wv3 = wy         * wx         * vy1 * vx1;
        const int y0c = min(max(y0, 0), H_ - 1);
        const int y1c = min(max(y1, 0), H_ - 1);
        const int x0c = min(max(x0, 0), W_ - 1);
        const int x1c = min(max(x1, 0), W_ - 1);
        const int pb  = min(max(x0, 0), W_ - 2);
        const float sA0 = (x0c == pb)     ? 1.f : 0.f;
        const float sB0 = (x1c == pb)     ? 1.f : 0.f;
        const float sA1 = (x0c == pb + 1) ? 1.f : 0.f;
        const float sB1 = (x1c == pb + 1) ? 1.f : 0.f;
        f32x4 wv;
        wv[0] = sA0 * wv0 + sB0 * wv1;
        wv[1] = sA1 * wv0 + sB1 * wv1;
        wv[2] = sA0 * wv2 + sB0 * wv3;
        wv[3] = sA1 * wv2 + sB1 * wv3;
        t_oab[e] = (uint32_t)((y0c * W_ + pb) * 4) |
                   ((uint32_t)((y1c * W_ + pb) * 4) << 16);
        t_wv[e] = wv;
    }
    __syncthreads();

    f32x4 acc[4][2];
#pragma unroll
    for (int i = 0; i < 4; ++i) { acc[i][0] = (f32x4)0.f; acc[i][1] = (f32x4)0.f; }

    const int wm = wave >> 1;
    const int wn = wave & 1;
    const int co0 = __builtin_amdgcn_readfirstlane(wm * 64);
    const int px0 = __builtin_amdgcn_readfirstlane(wn * 32);
    const int wqs = __builtin_amdgcn_readfirstlane(wave);
    const int m_l = lane & 15;
    const int k_l = (lane >> 4) << 3;

    const short* wrow[4];
#pragma unroll
    for (int mt = 0; mt < 4; ++mt)
        wrow[mt] = wbf + (size_t)(co0 + mt * 16 + m_l) * (C_ * KK_);

    for (int c0 = 0; c0 < C_; c0 += 32) {
        const char* xp[4];
#pragma unroll
        for (int dc = 0; dc < 4; ++dc)
            xp[dc] = (const char*)(x + ((size_t)(b * C_ + c0 + 4 * wqs + dc) << 12));
#pragma unroll
        for (int j = 0; j < 9; ++j) {
            short vs[4];
#pragma unroll
            for (int jj = 0; jj < 4; ++jj) {
                const int idx = j * 4 + jj;
                const int dc  = idx / 9;
                const int kk  = idx % 9;
                const uint32_t oab = t_oab[kk * 64 + lane];
                const f32x4    wv  = t_wv[kk * 64 + lane];
                f32x2 lo, hi;
                __builtin_memcpy(&lo, xp[dc] + (oab & 0xFFFFu), 8);
                __builtin_memcpy(&hi, xp[dc] + (oab >> 16), 8);
                vs[jj] = f2bf(wv[0] * lo[0] + wv[1] * lo[1] +
                              wv[2] * hi[0] + wv[3] * hi[1]);
            }
            short* cw = &colsf[lane * PADK + (wave * 9 + j) * 4];
            cw[0] = vs[0]; cw[1] = vs[1]; cw[2] = vs[2]; cw[3] = vs[3];
        }
        __syncthreads();
#pragma unroll
        for (int s = 0; s < 9; ++s) {
            const int krow = s * 32 + k_l;
            const short8 bfA = *reinterpret_cast<const short8*>(
                &colsf[(px0 + m_l) * PADK + krow]);
            const short8 bfB = *reinterpret_cast<const short8*>(
                &colsf[(px0 + 16 + m_l) * PADK + krow]);
            const int kglob = c0 * 9 + krow;
#pragma unroll
            for (int mt = 0; mt < 4; ++mt) {
                const short8 af = *reinterpret_cast<const short8*>(wrow[mt] + kglob);
                acc[mt][0] = __builtin_amdgcn_mfma_f32_16x16x32_bf16(
                    af, bfA, acc[mt][0], 0, 0, 0);
                acc[mt][1] = __builtin_amdgcn_mfma_f32_16x16x32_bf16(
                    af, bfB, acc[mt][1], 0, 0, 0);
            }
        }
        __syncthreads();
    }

    const int r0 = (lane >> 4) << 2;
#pragma unroll
    for (int mt = 0; mt < 4; ++mt) {
#pragma unroll
        for (int r = 0; r < 4; ++r) {
            const int co = co0 + mt * 16 + r0 + r;
            const float bv = bias[co];
            float* orow = out + ((size_t)(b * CO_ + co) * H_ + ho) * W_;
            orow[px0 + m_l]      = acc[mt][0][r] + bv;
            orow[px0 + 16 + m_l] = acc[mt][1][r] + bv;
        }
    }
}

extern "C" void kernel_launch(void* const* d_in, const int* in_sizes, int n_in,
                              void* d_out, int out_size, void* d_ws, size_t ws_size,
                              hipStream_t stream) {
    const float* x      = (const float*)d_in[0];
    const float* offset = (const float*)d_in[1];
    const float* weight = (const float*)d_in[2];
    const float* bias   = (const float*)d_in[3];
    float* out = (float*)d_out;
    (void)in_sizes; (void)n_in; (void)out_size;

    const size_t WPM_BYTES = (size_t)CO_ * C_ * KK_ * 2;          // 1,179,648
    const size_t XT_BYTES  = (size_t)B_ * H_ * W_ * C_ * 2;       // 16,777,216

    if (ws_size >= WPM_BYTES + XT_BYTES) {
        short* wpm = (short*)d_ws;
        short* xT  = (short*)((char*)d_ws + WPM_BYTES);
        hipLaunchKernelGGL(wperm16, dim3(288), dim3(256), 0, stream, weight, wpm);
        hipLaunchKernelGGL(xpose,   dim3(512), dim3(256), 0, stream, x, xT);
        hipLaunchKernelGGL(dcn_mfma4, dim3(512), dim3(1024), 0, stream,
                           xT, offset, wpm, bias, out);
    } else {
        short* wbf = (short*)d_ws;   // 1.18 MB
        hipLaunchKernelGGL(w2bf_fb, dim3(288), dim3(256), 0, stream,
                           weight, wbf, 73728);
        hipLaunchKernelGGL(dcn_mfma_fb, dim3(512), dim3(512), 0, stream,
                           x, offset, wbf, bias, out);
    }
}